// Round 5
// baseline (206.841 us; speedup 1.0000x reference)
//
#include <hip/hip_runtime.h>
#include <hip/hip_cooperative_groups.h>
#include <math.h>

namespace cg = cooperative_groups;

#define NN 2048
#define EE 65536
#define FF 7
#define SS 32
#define LL 16
#define BKT 64     // bucket slots per node, compile-time unrolled gather
#define OCAP 4096  // overflow capacity for deg > 64 (expected 0, correctness guard)

struct Params {
    const float *x; const int *ei;
    const float *W_in, *b_in, *W_msg, *b_msg, *W_ih, *W_hh, *b_ih, *b_hh;
    const float *W_mu, *b_mu, *W_ls, *b_ls, *W_d1, *b_d1, *W_d2, *b_d2;
    float *stA, *stB, *msgA, *msgB, *Abuf, *Bbuf;
    int *cnt, *ocnt, *olist, *bucket;
    float *out_adj, *out_mu, *out_ls;
};

__device__ __forceinline__ float fsig(float x) { return 1.f / (1.f + __expf(-x)); }
__device__ __forceinline__ float ftanh(float x) { return 1.f - 2.f / (__expf(2.f * x) + 1.f); }

// padded-64 unrolled gather (masked by deg, no bucket init needed) + GRU(residual)
__device__ __forceinline__ float gather_gru(int n, int s, int deg,
        const int* bucket, const int* ocnt, const int* olist,
        const float* msg_in, const float* st_in,
        const float* Wih, const float* Whh,
        const float* bih, const float* bhh) {
    const int* bk = bucket + n * BKT;
    int i0 = bk[s], i1 = bk[SS + s];
    float acc = 0.f;
#pragma unroll
    for (int k = 0; k < 32; k++) {
        int bsrc = __shfl(i0, k, 32);
        int src = (k < deg) ? bsrc : 0;          // clamp to valid row
        float v = msg_in[src * SS + s];
        acc += (k < deg) ? v : 0.f;              // mask value
    }
#pragma unroll
    for (int k = 0; k < 32; k++) {
        int kk = 32 + k;
        int bsrc = __shfl(i1, k, 32);
        int src = (kk < deg) ? bsrc : 0;
        float v = msg_in[src * SS + s];
        acc += (kk < deg) ? v : 0.f;
    }
    if (deg > BKT) {                              // correctness guard, expected never
        int oc = *ocnt; if (oc > OCAP) oc = OCAP;
        for (int i = 0; i < oc; i++)
            if (olist[2 * i + 1] == n) acc += msg_in[olist[2 * i] * SS + s];
    }
    float h0 = st_in[n * SS + s];
    float xr = bih[s], xz = bih[SS + s], xn = bih[2 * SS + s];
    float hr = bhh[s], hz = bhh[SS + s], hn = bhh[2 * SS + s];
#pragma unroll
    for (int k = 0; k < SS; k++) {
        float av = __shfl(acc, k, 32);
        float hv = __shfl(h0, k, 32);
        const float* wi = Wih + k * 3 * SS;
        const float* wh = Whh + k * 3 * SS;
        xr += av * wi[s];
        xz += av * wi[SS + s];
        xn += av * wi[2 * SS + s];
        hr += hv * wh[s];
        hz += hv * wh[SS + s];
        hn += hv * wh[2 * SS + s];
    }
    float rg = fsig(xr + hr);
    float zg = fsig(xz + hz);
    float ng = ftanh(xn + rg * hn);
    return h0 + (1.f - zg) * ng + zg * h0;
}

// One cooperative kernel: 256 blocks x 256 threads (1 block/CU, co-resident).
// Phases separated by grid.sync(); 65536 threads = 2048 nodes x 32 lanes = 65536 edges.
__global__ void __launch_bounds__(256) fused(Params p) {
    cg::grid_group grid = cg::this_grid();
    __shared__ float ldsAj[LL * 64];
    __shared__ float ldsBj[LL * 64];
    __shared__ float ldsT[64 * 65];

    int tid = threadIdx.x;
    int gid = blockIdx.x * 256 + tid;
    int n = gid >> 5, s = gid & 31;

    // ---- Phase 0: encoder + msg0; zero cnt/ocnt ----
    {
        const float* xr = p.x + n * FF;
        float acc = p.b_in[s];
#pragma unroll
        for (int k = 0; k < FF; k++) acc += xr[k] * p.W_in[k * SS + s];
        float st = fmaxf(acc, 0.f);
        p.stA[n * SS + s] = st;
        float m = p.b_msg[s];
#pragma unroll
        for (int k = 0; k < SS; k++) m += __shfl(st, k, 32) * p.W_msg[k * SS + s];
        p.msgA[n * SS + s] = fmaxf(m, 0.f);
        if (gid < NN) p.cnt[gid] = 0;
        if (gid == 0) *p.ocnt = 0;
    }
    grid.sync();

    // ---- Phase 1: bucket fill (one thread per edge) ----
    {
        int e = gid;
        int src = p.ei[e], dst = p.ei[EE + e];
        int slot = atomicAdd(&p.cnt[dst], 1);
        if (slot < BKT) p.bucket[dst * BKT + slot] = src;
        else {
            int oi = atomicAdd(p.ocnt, 1);
            if (oi < OCAP) { p.olist[2 * oi] = src; p.olist[2 * oi + 1] = dst; }
        }
    }
    grid.sync();

    int deg = p.cnt[n];

    // ---- Phase 2: round 0 (msgA,stA -> stB,msgB) ----
    {
        float st = gather_gru(n, s, deg, p.bucket, p.ocnt, p.olist, p.msgA, p.stA,
                              p.W_ih, p.W_hh, p.b_ih, p.b_hh);
        p.stB[n * SS + s] = st;
        const float* Wm = p.W_msg + 1 * SS * SS;
        const float* bm = p.b_msg + 1 * SS;
        float mv = bm[s];
#pragma unroll
        for (int k = 0; k < SS; k++) mv += __shfl(st, k, 32) * Wm[k * SS + s];
        p.msgB[n * SS + s] = fmaxf(mv, 0.f);
    }
    grid.sync();

    // ---- Phase 3: round 1 (msgB,stB -> stA,msgA) ----
    {
        float st = gather_gru(n, s, deg, p.bucket, p.ocnt, p.olist, p.msgB, p.stB,
                              p.W_ih + SS * 3 * SS, p.W_hh + SS * 3 * SS,
                              p.b_ih + 3 * SS, p.b_hh + 3 * SS);
        p.stA[n * SS + s] = st;
        const float* Wm = p.W_msg + 2 * SS * SS;
        const float* bm = p.b_msg + 2 * SS;
        float mv = bm[s];
#pragma unroll
        for (int k = 0; k < SS; k++) mv += __shfl(st, k, 32) * Wm[k * SS + s];
        p.msgA[n * SS + s] = fmaxf(mv, 0.f);
    }
    grid.sync();

    // ---- Phase 4: round 2 + heads + decoder operands ----
    {
        float st = gather_gru(n, s, deg, p.bucket, p.ocnt, p.olist, p.msgA, p.stA,
                              p.W_ih + 2 * SS * 3 * SS, p.W_hh + 2 * SS * 3 * SS,
                              p.b_ih + 2 * 3 * SS, p.b_hh + 2 * 3 * SS);
        int l = s & 15;
        const float* W = (s < 16) ? p.W_mu : p.W_ls;
        float v = (s < 16) ? p.b_mu[l] : p.b_ls[l];
#pragma unroll
        for (int k = 0; k < SS; k++) v += __shfl(st, k, 32) * W[k * LL + l];
        if (s < 16) p.out_mu[n * LL + l] = v; else p.out_ls[n * LL + l] = v;
        // A' = mu@W_d1[:L]+b_d1 (lanes 0-15), B = mu@W_d1[L:] (lanes 16-31);
        // mu row lives in lanes 0..15 so shfl k<16 is valid for all lanes.
        const float* Wd = p.W_d1 + ((s < 16) ? 0 : LL * LL);
        float ab = (s < 16) ? p.b_d1[l] : 0.f;
#pragma unroll
        for (int k = 0; k < LL; k++) ab += __shfl(v, k, 32) * Wd[k * LL + l];
        if (s < 16) p.Abuf[n * LL + l] = ab; else p.Bbuf[n * LL + l] = ab;
    }
    grid.sync();

    // ---- Phase 5: triangular-tiled decoder; block loops over its tiles ----
    float w[LL];
#pragma unroll
    for (int l = 0; l < LL; l++) w[l] = p.W_d2[l];
    float bd2 = p.b_d2[0];

    for (int t = blockIdx.x; t < 528; t += 256) {
        __syncthreads();   // protect LDS reuse across tile iterations
        int bi = (int)((65.f - sqrtf(4225.f - 8.f * (float)t)) * 0.5f);
        if (bi < 0) bi = 0;
        if (bi > 31) bi = 31;
        while (bi > 0 && (65 * bi - bi * bi) / 2 > t) bi--;
        while (bi < 31 && (65 * (bi + 1) - (bi + 1) * (bi + 1)) / 2 <= t) bi++;
        int bj = bi + (t - (65 * bi - bi * bi) / 2);
        int i0 = bi * 64, j0 = bj * 64;

        {   // stage j-side rows transposed into LDS (coalesced global float4 loads)
            int jr = tid >> 2, q = tid & 3;
            float4 va = ((const float4*)(p.Abuf + (size_t)(j0 + jr) * LL))[q];
            float4 vb = ((const float4*)(p.Bbuf + (size_t)(j0 + jr) * LL))[q];
            int l4 = q * 4;
            ldsAj[(l4 + 0) * 64 + jr] = va.x; ldsAj[(l4 + 1) * 64 + jr] = va.y;
            ldsAj[(l4 + 2) * 64 + jr] = va.z; ldsAj[(l4 + 3) * 64 + jr] = va.w;
            ldsBj[(l4 + 0) * 64 + jr] = vb.x; ldsBj[(l4 + 1) * 64 + jr] = vb.y;
            ldsBj[(l4 + 2) * 64 + jr] = vb.z; ldsBj[(l4 + 3) * 64 + jr] = vb.w;
        }
        __syncthreads();

        int jo = tid & 63;   // j lane
        int ig = tid >> 6;   // i sub-group 0..3
        float aj[LL], bjr[LL];
#pragma unroll
        for (int l = 0; l < LL; l++) {
            aj[l] = ldsAj[l * 64 + jo];
            bjr[l] = ldsBj[l * 64 + jo];
        }
        int j = j0 + jo;

#pragma unroll 2
        for (int ii = 0; ii < 16; ii++) {
            int i = i0 + ig * 16 + ii;
            const float4* Ai4 = (const float4*)(p.Abuf + (size_t)i * LL);
            const float4* Bi4 = (const float4*)(p.Bbuf + (size_t)i * LL);
            float4 a0 = Ai4[0], a1 = Ai4[1], a2 = Ai4[2], a3 = Ai4[3];
            float4 b0 = Bi4[0], b1 = Bi4[1], b2 = Bi4[2], b3 = Bi4[3];
            float ai[LL] = {a0.x, a0.y, a0.z, a0.w, a1.x, a1.y, a1.z, a1.w,
                            a2.x, a2.y, a2.z, a2.w, a3.x, a3.y, a3.z, a3.w};
            float bi_[LL] = {b0.x, b0.y, b0.z, b0.w, b1.x, b1.y, b1.z, b1.w,
                             b2.x, b2.y, b2.z, b2.w, b3.x, b3.y, b3.z, b3.w};
            float accij = 0.f, accji = 0.f;
#pragma unroll
            for (int l = 0; l < LL; l++) {
                accij += w[l] * fmaxf(ai[l] + bjr[l], 0.f);
                accji += w[l] * fmaxf(aj[l] + bi_[l], 0.f);
            }
            float logit = 0.5f * (accij + accji) + bd2;
            float pr = 1.f / (1.f + __expf(-logit));
            p.out_adj[(size_t)i * NN + j] = pr;
            ldsT[jo * 65 + ig * 16 + ii] = pr;
        }

        if (bi != bj) {  // transposed tile write via LDS (coalesced)
            __syncthreads();
            int jj = tid >> 2, qi = tid & 3;
            float v[16];
#pragma unroll
            for (int m = 0; m < 16; m++) v[m] = ldsT[jj * 65 + qi * 16 + m];
            float4* dst = (float4*)(p.out_adj + (size_t)(j0 + jj) * NN + i0 + qi * 16);
#pragma unroll
            for (int q4 = 0; q4 < 4; q4++)
                dst[q4] = make_float4(v[4 * q4], v[4 * q4 + 1], v[4 * q4 + 2], v[4 * q4 + 3]);
        }
    }
}

extern "C" void kernel_launch(void* const* d_in, const int* in_sizes, int n_in,
                              void* d_out, int out_size, void* d_ws, size_t ws_size,
                              hipStream_t stream) {
    Params p;
    p.x     = (const float*)d_in[0];
    p.ei    = (const int*)d_in[1];
    p.W_in  = (const float*)d_in[2];
    p.b_in  = (const float*)d_in[3];
    p.W_msg = (const float*)d_in[4];
    p.b_msg = (const float*)d_in[5];
    p.W_ih  = (const float*)d_in[6];
    p.W_hh  = (const float*)d_in[7];
    p.b_ih  = (const float*)d_in[8];
    p.b_hh  = (const float*)d_in[9];
    p.W_mu  = (const float*)d_in[10];
    p.b_mu  = (const float*)d_in[11];
    p.W_ls  = (const float*)d_in[12];
    p.b_ls  = (const float*)d_in[13];
    p.W_d1  = (const float*)d_in[14];
    p.b_d1  = (const float*)d_in[15];
    p.W_d2  = (const float*)d_in[16];
    p.b_d2  = (const float*)d_in[17];

    float* ws = (float*)d_ws;
    p.stA  = ws;                        // N*S
    p.stB  = p.stA + NN * SS;           // N*S
    p.msgA = p.stB + NN * SS;           // N*S
    p.msgB = p.msgA + NN * SS;          // N*S
    p.Abuf = p.msgB + NN * SS;          // N*L
    p.Bbuf = p.Abuf + NN * LL;          // N*L
    p.cnt  = (int*)(p.Bbuf + NN * LL);  // N
    p.ocnt = p.cnt + NN;                // 1
    p.olist = p.ocnt + 1;               // 2*OCAP
    p.bucket = p.olist + 2 * OCAP;      // N*BKT

    p.out_adj = (float*)d_out;
    p.out_mu  = p.out_adj + (size_t)NN * NN;
    p.out_ls  = p.out_mu + NN * LL;

    void* args[] = { &p };
    hipLaunchCooperativeKernel((const void*)fused, dim3(256), dim3(256), args, 0, stream);
}

// Round 6
// 121.130 us; speedup vs baseline: 1.7076x; 1.7076x over previous
//
#include <hip/hip_runtime.h>
#include <math.h>

#define NN 2048
#define EE 65536
#define FF 7
#define SS 32
#define LL 16
#define BKT 64     // bucket slots per node, compile-time unrolled gather
#define OCAP 4096  // overflow capacity for deg > 64 (expected 0, correctness guard)
#define NBLK 256   // cooperative grid size (1 block per CU)

struct Params {
    const float *x; const int *ei;
    const float *W_in, *b_in, *W_msg, *b_msg, *W_ih, *W_hh, *b_ih, *b_hh;
    const float *W_mu, *b_mu, *W_ls, *b_ls, *W_d1, *b_d1;
    float *stA, *stB, *msgA, *msgB, *Abuf, *Bbuf;
    int *cnt, *ocnt, *olist, *bucket, *bar;
    float *out_mu, *out_ls;
};

__device__ __forceinline__ float fsig(float x) { return 1.f / (1.f + __expf(-x)); }
__device__ __forceinline__ float ftanh(float x) { return 1.f - 2.f / (__expf(2.f * x) + 1.f); }

// Lightweight grid barrier: leader-only agent-scope atomic + s_sleep spin.
// bar[idx] must be zero at kernel entry (memset'd by host each call).
__device__ __forceinline__ void gbar(int* bar) {
    __syncthreads();
    if (threadIdx.x == 0) {
        __hip_atomic_fetch_add(bar, 1, __ATOMIC_ACQ_REL, __HIP_MEMORY_SCOPE_AGENT);
        while (__hip_atomic_load(bar, __ATOMIC_ACQUIRE, __HIP_MEMORY_SCOPE_AGENT) < NBLK)
            __builtin_amdgcn_s_sleep(8);
    }
    __syncthreads();
}

// padded-64 unrolled gather (masked by deg, no bucket init needed) + GRU(residual)
__device__ __forceinline__ float gather_gru(int n, int s, int deg,
        const int* bucket, const int* ocnt, const int* olist,
        const float* msg_in, const float* st_in,
        const float* Wih, const float* Whh,
        const float* bih, const float* bhh) {
    const int* bk = bucket + n * BKT;
    int i0 = bk[s], i1 = bk[SS + s];
    float acc = 0.f;
#pragma unroll
    for (int k = 0; k < 32; k++) {
        int bsrc = __shfl(i0, k, 32);
        int src = (k < deg) ? bsrc : 0;          // clamp to valid row
        float v = msg_in[src * SS + s];
        acc += (k < deg) ? v : 0.f;              // mask value
    }
#pragma unroll
    for (int k = 0; k < 32; k++) {
        int kk = 32 + k;
        int bsrc = __shfl(i1, k, 32);
        int src = (kk < deg) ? bsrc : 0;
        float v = msg_in[src * SS + s];
        acc += (kk < deg) ? v : 0.f;
    }
    if (deg > BKT) {                              // correctness guard, expected never
        int oc = *ocnt; if (oc > OCAP) oc = OCAP;
        for (int i = 0; i < oc; i++)
            if (olist[2 * i + 1] == n) acc += msg_in[olist[2 * i] * SS + s];
    }
    float h0 = st_in[n * SS + s];
    float xr = bih[s], xz = bih[SS + s], xn = bih[2 * SS + s];
    float hr = bhh[s], hz = bhh[SS + s], hn = bhh[2 * SS + s];
#pragma unroll
    for (int k = 0; k < SS; k++) {
        float av = __shfl(acc, k, 32);
        float hv = __shfl(h0, k, 32);
        const float* wi = Wih + k * 3 * SS;
        const float* wh = Whh + k * 3 * SS;
        xr += av * wi[s];
        xz += av * wi[SS + s];
        xn += av * wi[2 * SS + s];
        hr += hv * wh[s];
        hz += hv * wh[SS + s];
        hn += hv * wh[2 * SS + s];
    }
    float rg = fsig(xr + hr);
    float zg = fsig(xz + hz);
    float ng = ftanh(xn + rg * hn);
    return h0 + (1.f - zg) * ng + zg * h0;
}

// Cooperative GNN kernel: 256 blocks x 256 threads (1 block/CU), 3 hand-rolled
// grid barriers. 65536 threads = 2048 nodes x 32 lanes = 65536 edges.
__global__ void __launch_bounds__(256) gnn(Params p) {
    int tid = threadIdx.x;
    int gid = blockIdx.x * 256 + tid;
    int n = gid >> 5, s = gid & 31;

    // ---- Phase 0: encoder + msg0; bucket fill (independent of encoder) ----
    {
        int e = gid;
        int src = p.ei[e], dst = p.ei[EE + e];
        int slot = atomicAdd(&p.cnt[dst], 1);
        if (slot < BKT) p.bucket[dst * BKT + slot] = src;
        else {
            int oi = atomicAdd(p.ocnt, 1);
            if (oi < OCAP) { p.olist[2 * oi] = src; p.olist[2 * oi + 1] = dst; }
        }
        const float* xr = p.x + n * FF;
        float acc = p.b_in[s];
#pragma unroll
        for (int k = 0; k < FF; k++) acc += xr[k] * p.W_in[k * SS + s];
        float st = fmaxf(acc, 0.f);
        p.stA[n * SS + s] = st;
        float m = p.b_msg[s];
#pragma unroll
        for (int k = 0; k < SS; k++) m += __shfl(st, k, 32) * p.W_msg[k * SS + s];
        p.msgA[n * SS + s] = fmaxf(m, 0.f);
    }
    gbar(p.bar + 0);

    int deg = p.cnt[n];

    // ---- Phase 1: round 0 (msgA,stA -> stB,msgB) ----
    {
        float st = gather_gru(n, s, deg, p.bucket, p.ocnt, p.olist, p.msgA, p.stA,
                              p.W_ih, p.W_hh, p.b_ih, p.b_hh);
        p.stB[n * SS + s] = st;
        const float* Wm = p.W_msg + 1 * SS * SS;
        const float* bm = p.b_msg + 1 * SS;
        float mv = bm[s];
#pragma unroll
        for (int k = 0; k < SS; k++) mv += __shfl(st, k, 32) * Wm[k * SS + s];
        p.msgB[n * SS + s] = fmaxf(mv, 0.f);
    }
    gbar(p.bar + 1);

    // ---- Phase 2: round 1 (msgB,stB -> stA,msgA) ----
    {
        float st = gather_gru(n, s, deg, p.bucket, p.ocnt, p.olist, p.msgB, p.stB,
                              p.W_ih + SS * 3 * SS, p.W_hh + SS * 3 * SS,
                              p.b_ih + 3 * SS, p.b_hh + 3 * SS);
        p.stA[n * SS + s] = st;
        const float* Wm = p.W_msg + 2 * SS * SS;
        const float* bm = p.b_msg + 2 * SS;
        float mv = bm[s];
#pragma unroll
        for (int k = 0; k < SS; k++) mv += __shfl(st, k, 32) * Wm[k * SS + s];
        p.msgA[n * SS + s] = fmaxf(mv, 0.f);
    }
    gbar(p.bar + 2);

    // ---- Phase 3: round 2 + heads + decoder operands ----
    {
        float st = gather_gru(n, s, deg, p.bucket, p.ocnt, p.olist, p.msgA, p.stA,
                              p.W_ih + 2 * SS * 3 * SS, p.W_hh + 2 * SS * 3 * SS,
                              p.b_ih + 2 * 3 * SS, p.b_hh + 2 * 3 * SS);
        int l = s & 15;
        const float* W = (s < 16) ? p.W_mu : p.W_ls;
        float v = (s < 16) ? p.b_mu[l] : p.b_ls[l];
#pragma unroll
        for (int k = 0; k < SS; k++) v += __shfl(st, k, 32) * W[k * LL + l];
        if (s < 16) p.out_mu[n * LL + l] = v; else p.out_ls[n * LL + l] = v;
        // A' = mu@W_d1[:L]+b_d1 (lanes 0-15), B = mu@W_d1[L:] (lanes 16-31);
        // mu row lives in lanes 0..15 so shfl k<16 is valid for all lanes.
        const float* Wd = p.W_d1 + ((s < 16) ? 0 : LL * LL);
        float ab = (s < 16) ? p.b_d1[l] : 0.f;
#pragma unroll
        for (int k = 0; k < LL; k++) ab += __shfl(v, k, 32) * Wd[k * LL + l];
        if (s < 16) p.Abuf[n * LL + l] = ab; else p.Bbuf[n * LL + l] = ab;
    }
}

// Triangular-tiled decoder: 64x64 (bi,bj) tile with bi<=bj, computes symmetric
// prob once per unordered pair, writes tile + transpose (via LDS, coalesced).
__global__ __launch_bounds__(256) void dec_kernel(const float* __restrict__ Abuf,
                                                  const float* __restrict__ Bbuf,
                                                  const float* __restrict__ W_d2,
                                                  const float* __restrict__ b_d2,
                                                  float* __restrict__ out) {
    __shared__ float ldsAj[LL * 64];
    __shared__ float ldsBj[LL * 64];
    __shared__ float ldsT[64 * 65];
    int t = blockIdx.x;
    int bi = (int)((65.f - sqrtf(4225.f - 8.f * (float)t)) * 0.5f);
    if (bi < 0) bi = 0;
    if (bi > 31) bi = 31;
    while (bi > 0 && (65 * bi - bi * bi) / 2 > t) bi--;
    while (bi < 31 && (65 * (bi + 1) - (bi + 1) * (bi + 1)) / 2 <= t) bi++;
    int bj = bi + (t - (65 * bi - bi * bi) / 2);
    int i0 = bi * 64, j0 = bj * 64;
    int tid = threadIdx.x;

    {   // stage j-side rows transposed into LDS (coalesced global float4 loads)
        int jr = tid >> 2, q = tid & 3;
        float4 va = ((const float4*)(Abuf + (size_t)(j0 + jr) * LL))[q];
        float4 vb = ((const float4*)(Bbuf + (size_t)(j0 + jr) * LL))[q];
        int l4 = q * 4;
        ldsAj[(l4 + 0) * 64 + jr] = va.x; ldsAj[(l4 + 1) * 64 + jr] = va.y;
        ldsAj[(l4 + 2) * 64 + jr] = va.z; ldsAj[(l4 + 3) * 64 + jr] = va.w;
        ldsBj[(l4 + 0) * 64 + jr] = vb.x; ldsBj[(l4 + 1) * 64 + jr] = vb.y;
        ldsBj[(l4 + 2) * 64 + jr] = vb.z; ldsBj[(l4 + 3) * 64 + jr] = vb.w;
    }
    __syncthreads();

    int jo = tid & 63;   // j lane
    int ig = tid >> 6;   // i sub-group 0..3
    float aj[LL], bjr[LL], w[LL];
#pragma unroll
    for (int l = 0; l < LL; l++) {
        aj[l] = ldsAj[l * 64 + jo];
        bjr[l] = ldsBj[l * 64 + jo];
        w[l] = W_d2[l];
    }
    float bd2 = b_d2[0];
    int j = j0 + jo;

#pragma unroll 2
    for (int ii = 0; ii < 16; ii++) {
        int i = i0 + ig * 16 + ii;
        const float4* Ai4 = (const float4*)(Abuf + (size_t)i * LL);
        const float4* Bi4 = (const float4*)(Bbuf + (size_t)i * LL);
        float4 a0 = Ai4[0], a1 = Ai4[1], a2 = Ai4[2], a3 = Ai4[3];
        float4 b0 = Bi4[0], b1 = Bi4[1], b2 = Bi4[2], b3 = Bi4[3];
        float ai[LL] = {a0.x, a0.y, a0.z, a0.w, a1.x, a1.y, a1.z, a1.w,
                        a2.x, a2.y, a2.z, a2.w, a3.x, a3.y, a3.z, a3.w};
        float bi_[LL] = {b0.x, b0.y, b0.z, b0.w, b1.x, b1.y, b1.z, b1.w,
                         b2.x, b2.y, b2.z, b2.w, b3.x, b3.y, b3.z, b3.w};
        float accij = 0.f, accji = 0.f;
#pragma unroll
        for (int l = 0; l < LL; l++) {
            accij += w[l] * fmaxf(ai[l] + bjr[l], 0.f);
            accji += w[l] * fmaxf(aj[l] + bi_[l], 0.f);
        }
        float logit = 0.5f * (accij + accji) + bd2;
        float p = 1.f / (1.f + __expf(-logit));
        out[(size_t)i * NN + j] = p;
        ldsT[jo * 65 + ig * 16 + ii] = p;
    }

    if (bi != bj) {  // transposed tile write via LDS (coalesced)
        __syncthreads();
        int jj = tid >> 2, qi = tid & 3;
        float v[16];
#pragma unroll
        for (int m = 0; m < 16; m++) v[m] = ldsT[jj * 65 + qi * 16 + m];
        float4* dst = (float4*)(out + (size_t)(j0 + jj) * NN + i0 + qi * 16);
#pragma unroll
        for (int q4 = 0; q4 < 4; q4++)
            dst[q4] = make_float4(v[4 * q4], v[4 * q4 + 1], v[4 * q4 + 2], v[4 * q4 + 3]);
    }
}

extern "C" void kernel_launch(void* const* d_in, const int* in_sizes, int n_in,
                              void* d_out, int out_size, void* d_ws, size_t ws_size,
                              hipStream_t stream) {
    Params p;
    p.x     = (const float*)d_in[0];
    p.ei    = (const int*)d_in[1];
    p.W_in  = (const float*)d_in[2];
    p.b_in  = (const float*)d_in[3];
    p.W_msg = (const float*)d_in[4];
    p.b_msg = (const float*)d_in[5];
    p.W_ih  = (const float*)d_in[6];
    p.W_hh  = (const float*)d_in[7];
    p.b_ih  = (const float*)d_in[8];
    p.b_hh  = (const float*)d_in[9];
    p.W_mu  = (const float*)d_in[10];
    p.b_mu  = (const float*)d_in[11];
    p.W_ls  = (const float*)d_in[12];
    p.b_ls  = (const float*)d_in[13];
    p.W_d1  = (const float*)d_in[14];
    p.b_d1  = (const float*)d_in[15];
    const float* W_d2 = (const float*)d_in[16];
    const float* b_d2 = (const float*)d_in[17];

    float* ws = (float*)d_ws;
    p.stA  = ws;                        // N*S
    p.stB  = p.stA + NN * SS;           // N*S
    p.msgA = p.stB + NN * SS;           // N*S
    p.msgB = p.msgA + NN * SS;          // N*S
    p.Abuf = p.msgB + NN * SS;          // N*L
    p.Bbuf = p.Abuf + NN * LL;          // N*L
    p.cnt  = (int*)(p.Bbuf + NN * LL);  // N      (memset region start)
    p.ocnt = p.cnt + NN;                // 1
    p.bar  = p.ocnt + 1;                // 8      (memset region end)
    p.olist = p.bar + 8;                // 2*OCAP
    p.bucket = p.olist + 2 * OCAP;      // N*BKT

    float* out_adj = (float*)d_out;
    p.out_mu  = out_adj + (size_t)NN * NN;
    p.out_ls  = p.out_mu + NN * LL;

    // zero cnt + ocnt + barrier counters (one small memset, graph-capturable)
    hipMemsetAsync(p.cnt, 0, (NN + 1 + 8) * sizeof(int), stream);

    void* args[] = { &p };
    hipLaunchCooperativeKernel((const void*)gnn, dim3(NBLK), dim3(256), args, 0, stream);

    dec_kernel<<<528, 256, 0, stream>>>(p.Abuf, p.Bbuf, W_d2, b_d2, out_adj);
}

// Round 7
// 108.598 us; speedup vs baseline: 1.9047x; 1.1154x over previous
//
#include <hip/hip_runtime.h>
#include <math.h>

#define NN 2048
#define EE 65536
#define FF 7
#define SS 32
#define LL 16
#define BKT 64     // bucket slots per node, compile-time unrolled gather
#define OCAP 4096  // overflow capacity for deg > 64 (expected 0, correctness guard)
#define NBLK 256   // cooperative grid size (1 block per CU)

struct Params {
    const float *x; const int *ei;
    const float *W_in, *b_in, *W_msg, *b_msg, *W_ih, *W_hh, *b_ih, *b_hh;
    const float *W_mu, *b_mu, *W_ls, *b_ls, *W_d1, *b_d1;
    float *stA, *stB, *msgA, *msgB, *Abuf, *Bbuf;
    int *cnt, *ocnt, *olist, *bucket, *flags;
    float *out_mu, *out_ls;
};

__device__ __forceinline__ float fsig(float x) { return 1.f / (1.f + __expf(-x)); }
__device__ __forceinline__ float ftanh(float x) { return 1.f - 2.f / (__expf(2.f * x) + 1.f); }

// Grid barrier with ONE release-fence + relaxed per-block flag + relaxed polls
// + ONE acquire-fence. No ACQ_REL RMW storm, no per-poll buffer_inv.
// flags[] zeroed by host memset each call; phase = 1,2,3 monotonic per call.
__device__ __forceinline__ void gbar(int* flags, int phase) {
    __syncthreads();
    if (threadIdx.x < 64) {
        if (threadIdx.x == 0) {
            __builtin_amdgcn_fence(__ATOMIC_RELEASE, "agent");   // one L2 writeback
            __hip_atomic_store(flags + blockIdx.x, phase,
                               __ATOMIC_RELAXED, __HIP_MEMORY_SCOPE_AGENT);
        }
        int l = threadIdx.x;
        for (;;) {
            int a = __hip_atomic_load(flags + l,       __ATOMIC_RELAXED, __HIP_MEMORY_SCOPE_AGENT);
            int b = __hip_atomic_load(flags + l + 64,  __ATOMIC_RELAXED, __HIP_MEMORY_SCOPE_AGENT);
            int c = __hip_atomic_load(flags + l + 128, __ATOMIC_RELAXED, __HIP_MEMORY_SCOPE_AGENT);
            int d = __hip_atomic_load(flags + l + 192, __ATOMIC_RELAXED, __HIP_MEMORY_SCOPE_AGENT);
            if (__all(a >= phase && b >= phase && c >= phase && d >= phase)) break;
            __builtin_amdgcn_s_sleep(1);
        }
        __builtin_amdgcn_fence(__ATOMIC_ACQUIRE, "agent");       // one L1/L2 invalidate
    }
    __syncthreads();
}

// padded-64 unrolled gather (masked by deg, no bucket init needed) + GRU(residual)
__device__ __forceinline__ float gather_gru(int n, int s, int deg,
        const int* bucket, const int* ocnt, const int* olist,
        const float* msg_in, const float* st_in,
        const float* Wih, const float* Whh,
        const float* bih, const float* bhh) {
    const int* bk = bucket + n * BKT;
    int i0 = bk[s], i1 = bk[SS + s];
    float acc = 0.f;
#pragma unroll
    for (int k = 0; k < 32; k++) {
        int bsrc = __shfl(i0, k, 32);
        int src = (k < deg) ? bsrc : 0;          // clamp to valid row
        float v = msg_in[src * SS + s];
        acc += (k < deg) ? v : 0.f;              // mask value
    }
#pragma unroll
    for (int k = 0; k < 32; k++) {
        int kk = 32 + k;
        int bsrc = __shfl(i1, k, 32);
        int src = (kk < deg) ? bsrc : 0;
        float v = msg_in[src * SS + s];
        acc += (kk < deg) ? v : 0.f;
    }
    if (deg > BKT) {                              // correctness guard, expected never
        int oc = *ocnt; if (oc > OCAP) oc = OCAP;
        for (int i = 0; i < oc; i++)
            if (olist[2 * i + 1] == n) acc += msg_in[olist[2 * i] * SS + s];
    }
    float h0 = st_in[n * SS + s];
    float xr = bih[s], xz = bih[SS + s], xn = bih[2 * SS + s];
    float hr = bhh[s], hz = bhh[SS + s], hn = bhh[2 * SS + s];
#pragma unroll
    for (int k = 0; k < SS; k++) {
        float av = __shfl(acc, k, 32);
        float hv = __shfl(h0, k, 32);
        const float* wi = Wih + k * 3 * SS;
        const float* wh = Whh + k * 3 * SS;
        xr += av * wi[s];
        xz += av * wi[SS + s];
        xn += av * wi[2 * SS + s];
        hr += hv * wh[s];
        hz += hv * wh[SS + s];
        hn += hv * wh[2 * SS + s];
    }
    float rg = fsig(xr + hr);
    float zg = fsig(xz + hz);
    float ng = ftanh(xn + rg * hn);
    return h0 + (1.f - zg) * ng + zg * h0;
}

// Cooperative GNN kernel: 256 blocks x 256 threads (1 block/CU), 3 grid barriers.
// 65536 threads = 2048 nodes x 32 lanes = 65536 edges.
__global__ void __launch_bounds__(256) gnn(Params p) {
    int tid = threadIdx.x;
    int gid = blockIdx.x * 256 + tid;
    int n = gid >> 5, s = gid & 31;

    // ---- Phase 0: encoder + msg0; bucket fill (independent of encoder) ----
    {
        int e = gid;
        int src = p.ei[e], dst = p.ei[EE + e];
        int slot = atomicAdd(&p.cnt[dst], 1);
        if (slot < BKT) p.bucket[dst * BKT + slot] = src;
        else {
            int oi = atomicAdd(p.ocnt, 1);
            if (oi < OCAP) { p.olist[2 * oi] = src; p.olist[2 * oi + 1] = dst; }
        }
        const float* xr = p.x + n * FF;
        float acc = p.b_in[s];
#pragma unroll
        for (int k = 0; k < FF; k++) acc += xr[k] * p.W_in[k * SS + s];
        float st = fmaxf(acc, 0.f);
        p.stA[n * SS + s] = st;
        float m = p.b_msg[s];
#pragma unroll
        for (int k = 0; k < SS; k++) m += __shfl(st, k, 32) * p.W_msg[k * SS + s];
        p.msgA[n * SS + s] = fmaxf(m, 0.f);
    }
    gbar(p.flags, 1);

    int deg = p.cnt[n];

    // ---- Phase 1: round 0 (msgA,stA -> stB,msgB) ----
    {
        float st = gather_gru(n, s, deg, p.bucket, p.ocnt, p.olist, p.msgA, p.stA,
                              p.W_ih, p.W_hh, p.b_ih, p.b_hh);
        p.stB[n * SS + s] = st;
        const float* Wm = p.W_msg + 1 * SS * SS;
        const float* bm = p.b_msg + 1 * SS;
        float mv = bm[s];
#pragma unroll
        for (int k = 0; k < SS; k++) mv += __shfl(st, k, 32) * Wm[k * SS + s];
        p.msgB[n * SS + s] = fmaxf(mv, 0.f);
    }
    gbar(p.flags, 2);

    // ---- Phase 2: round 1 (msgB,stB -> stA,msgA) ----
    {
        float st = gather_gru(n, s, deg, p.bucket, p.ocnt, p.olist, p.msgB, p.stB,
                              p.W_ih + SS * 3 * SS, p.W_hh + SS * 3 * SS,
                              p.b_ih + 3 * SS, p.b_hh + 3 * SS);
        p.stA[n * SS + s] = st;
        const float* Wm = p.W_msg + 2 * SS * SS;
        const float* bm = p.b_msg + 2 * SS;
        float mv = bm[s];
#pragma unroll
        for (int k = 0; k < SS; k++) mv += __shfl(st, k, 32) * Wm[k * SS + s];
        p.msgA[n * SS + s] = fmaxf(mv, 0.f);
    }
    gbar(p.flags, 3);

    // ---- Phase 3: round 2 + heads + decoder operands ----
    {
        float st = gather_gru(n, s, deg, p.bucket, p.ocnt, p.olist, p.msgA, p.stA,
                              p.W_ih + 2 * SS * 3 * SS, p.W_hh + 2 * SS * 3 * SS,
                              p.b_ih + 2 * 3 * SS, p.b_hh + 2 * 3 * SS);
        int l = s & 15;
        const float* W = (s < 16) ? p.W_mu : p.W_ls;
        float v = (s < 16) ? p.b_mu[l] : p.b_ls[l];
#pragma unroll
        for (int k = 0; k < SS; k++) v += __shfl(st, k, 32) * W[k * LL + l];
        if (s < 16) p.out_mu[n * LL + l] = v; else p.out_ls[n * LL + l] = v;
        // A' = mu@W_d1[:L]+b_d1 (lanes 0-15), B = mu@W_d1[L:] (lanes 16-31);
        // mu row lives in lanes 0..15 so shfl k<16 is valid for all lanes.
        const float* Wd = p.W_d1 + ((s < 16) ? 0 : LL * LL);
        float ab = (s < 16) ? p.b_d1[l] : 0.f;
#pragma unroll
        for (int k = 0; k < LL; k++) ab += __shfl(v, k, 32) * Wd[k * LL + l];
        if (s < 16) p.Abuf[n * LL + l] = ab; else p.Bbuf[n * LL + l] = ab;
    }
}

// Triangular-tiled decoder: 64x64 (bi,bj) tile with bi<=bj, computes symmetric
// prob once per unordered pair, writes tile + transpose (via LDS, coalesced).
__global__ __launch_bounds__(256) void dec_kernel(const float* __restrict__ Abuf,
                                                  const float* __restrict__ Bbuf,
                                                  const float* __restrict__ W_d2,
                                                  const float* __restrict__ b_d2,
                                                  float* __restrict__ out) {
    __shared__ float ldsAj[LL * 64];
    __shared__ float ldsBj[LL * 64];
    __shared__ float ldsT[64 * 65];
    int t = blockIdx.x;
    int bi = (int)((65.f - sqrtf(4225.f - 8.f * (float)t)) * 0.5f);
    if (bi < 0) bi = 0;
    if (bi > 31) bi = 31;
    while (bi > 0 && (65 * bi - bi * bi) / 2 > t) bi--;
    while (bi < 31 && (65 * (bi + 1) - (bi + 1) * (bi + 1)) / 2 <= t) bi++;
    int bj = bi + (t - (65 * bi - bi * bi) / 2);
    int i0 = bi * 64, j0 = bj * 64;
    int tid = threadIdx.x;

    {   // stage j-side rows transposed into LDS (coalesced global float4 loads)
        int jr = tid >> 2, q = tid & 3;
        float4 va = ((const float4*)(Abuf + (size_t)(j0 + jr) * LL))[q];
        float4 vb = ((const float4*)(Bbuf + (size_t)(j0 + jr) * LL))[q];
        int l4 = q * 4;
        ldsAj[(l4 + 0) * 64 + jr] = va.x; ldsAj[(l4 + 1) * 64 + jr] = va.y;
        ldsAj[(l4 + 2) * 64 + jr] = va.z; ldsAj[(l4 + 3) * 64 + jr] = va.w;
        ldsBj[(l4 + 0) * 64 + jr] = vb.x; ldsBj[(l4 + 1) * 64 + jr] = vb.y;
        ldsBj[(l4 + 2) * 64 + jr] = vb.z; ldsBj[(l4 + 3) * 64 + jr] = vb.w;
    }
    __syncthreads();

    int jo = tid & 63;   // j lane
    int ig = tid >> 6;   // i sub-group 0..3
    float aj[LL], bjr[LL], w[LL];
#pragma unroll
    for (int l = 0; l < LL; l++) {
        aj[l] = ldsAj[l * 64 + jo];
        bjr[l] = ldsBj[l * 64 + jo];
        w[l] = W_d2[l];
    }
    float bd2 = b_d2[0];
    int j = j0 + jo;

#pragma unroll 2
    for (int ii = 0; ii < 16; ii++) {
        int i = i0 + ig * 16 + ii;
        const float4* Ai4 = (const float4*)(Abuf + (size_t)i * LL);
        const float4* Bi4 = (const float4*)(Bbuf + (size_t)i * LL);
        float4 a0 = Ai4[0], a1 = Ai4[1], a2 = Ai4[2], a3 = Ai4[3];
        float4 b0 = Bi4[0], b1 = Bi4[1], b2 = Bi4[2], b3 = Bi4[3];
        float ai[LL] = {a0.x, a0.y, a0.z, a0.w, a1.x, a1.y, a1.z, a1.w,
                        a2.x, a2.y, a2.z, a2.w, a3.x, a3.y, a3.z, a3.w};
        float bi_[LL] = {b0.x, b0.y, b0.z, b0.w, b1.x, b1.y, b1.z, b1.w,
                         b2.x, b2.y, b2.z, b2.w, b3.x, b3.y, b3.z, b3.w};
        float accij = 0.f, accji = 0.f;
#pragma unroll
        for (int l = 0; l < LL; l++) {
            accij += w[l] * fmaxf(ai[l] + bjr[l], 0.f);
            accji += w[l] * fmaxf(aj[l] + bi_[l], 0.f);
        }
        float logit = 0.5f * (accij + accji) + bd2;
        float p = 1.f / (1.f + __expf(-logit));
        out[(size_t)i * NN + j] = p;
        ldsT[jo * 65 + ig * 16 + ii] = p;
    }

    if (bi != bj) {  // transposed tile write via LDS (coalesced)
        __syncthreads();
        int jj = tid >> 2, qi = tid & 3;
        float v[16];
#pragma unroll
        for (int m = 0; m < 16; m++) v[m] = ldsT[jj * 65 + qi * 16 + m];
        float4* dst = (float4*)(out + (size_t)(j0 + jj) * NN + i0 + qi * 16);
#pragma unroll
        for (int q4 = 0; q4 < 4; q4++)
            dst[q4] = make_float4(v[4 * q4], v[4 * q4 + 1], v[4 * q4 + 2], v[4 * q4 + 3]);
    }
}

extern "C" void kernel_launch(void* const* d_in, const int* in_sizes, int n_in,
                              void* d_out, int out_size, void* d_ws, size_t ws_size,
                              hipStream_t stream) {
    Params p;
    p.x     = (const float*)d_in[0];
    p.ei    = (const int*)d_in[1];
    p.W_in  = (const float*)d_in[2];
    p.b_in  = (const float*)d_in[3];
    p.W_msg = (const float*)d_in[4];
    p.b_msg = (const float*)d_in[5];
    p.W_ih  = (const float*)d_in[6];
    p.W_hh  = (const float*)d_in[7];
    p.b_ih  = (const float*)d_in[8];
    p.b_hh  = (const float*)d_in[9];
    p.W_mu  = (const float*)d_in[10];
    p.b_mu  = (const float*)d_in[11];
    p.W_ls  = (const float*)d_in[12];
    p.b_ls  = (const float*)d_in[13];
    p.W_d1  = (const float*)d_in[14];
    p.b_d1  = (const float*)d_in[15];
    const float* W_d2 = (const float*)d_in[16];
    const float* b_d2 = (const float*)d_in[17];

    float* ws = (float*)d_ws;
    p.stA  = ws;                        // N*S
    p.stB  = p.stA + NN * SS;           // N*S
    p.msgA = p.stB + NN * SS;           // N*S
    p.msgB = p.msgA + NN * SS;          // N*S
    p.Abuf = p.msgB + NN * SS;          // N*L
    p.Bbuf = p.Abuf + NN * LL;          // N*L
    p.cnt  = (int*)(p.Bbuf + NN * LL);  // N      (memset region start)
    p.ocnt = p.cnt + NN;                // 1
    p.flags = p.ocnt + 1;               // NBLK   (memset region end)
    p.olist = p.flags + NBLK;           // 2*OCAP
    p.bucket = p.olist + 2 * OCAP;      // N*BKT

    float* out_adj = (float*)d_out;
    p.out_mu  = out_adj + (size_t)NN * NN;
    p.out_ls  = p.out_mu + NN * LL;

    // zero cnt + ocnt + barrier flags (one small memset, graph-capturable)
    hipMemsetAsync(p.cnt, 0, (NN + 1 + NBLK) * sizeof(int), stream);

    void* args[] = { &p };
    hipLaunchCooperativeKernel((const void*)gnn, dim3(NBLK), dim3(256), args, 0, stream);

    dec_kernel<<<528, 256, 0, stream>>>(p.Abuf, p.Bbuf, W_d2, b_d2, out_adj);
}

// Round 8
// 68.569 us; speedup vs baseline: 3.0165x; 1.5838x over previous
//
#include <hip/hip_runtime.h>
#include <math.h>

#define NN 2048
#define EE 65536
#define FF 7
#define SS 32
#define LL 16
#define BKT 64     // bucket slots per node, compile-time unrolled gather
#define OCAP 4096  // overflow capacity for deg > 64 (expected 0, correctness guard)
#define NBLK 256   // grid size (1 block per CU, co-resident)

struct Params {
    const float *x; const int *ei;
    const float *W_in, *b_in, *W_msg, *b_msg, *W_ih, *W_hh, *b_ih, *b_hh;
    const float *W_mu, *b_mu, *W_ls, *b_ls, *W_d1, *b_d1;
    float *st0, *st1, *st2, *msg0, *msg1, *msg2, *Abuf, *Bbuf;
    int *cnt, *ocnt, *olist, *bucket, *flags;
    float *out_mu, *out_ls;
};

__device__ __forceinline__ float fsig(float x) { return 1.f / (1.f + __expf(-x)); }
__device__ __forceinline__ float ftanh(float x) { return 1.f - 2.f / (__expf(2.f * x) + 1.f); }

// write-through store (sc0 sc1 -> coherent point); relaxed, no fence
__device__ __forceinline__ void stwt(float* p, float v) {
    __hip_atomic_store(p, v, __ATOMIC_RELAXED, __HIP_MEMORY_SCOPE_SYSTEM);
}
__device__ __forceinline__ void stwt_i(int* p, int v) {
    __hip_atomic_store(p, v, __ATOMIC_RELAXED, __HIP_MEMORY_SCOPE_SYSTEM);
}

// Fence-free grid barrier. Correctness relies on:
//  (a) all cross-block data written via stwt (already at coherent point),
//  (b) __syncthreads() draining vmcnt for every wave before the flag store,
//  (c) consumers reading only buffers never cached earlier in this dispatch.
// flags[] zeroed by host memset each call; phase = 1,2,3 monotonic per call.
__device__ __forceinline__ void gbar(int* flags, int phase) {
    __syncthreads();   // all waves drained (compiler emits s_waitcnt vmcnt(0))
    if (threadIdx.x == 0)
        __hip_atomic_store(flags + blockIdx.x, phase,
                           __ATOMIC_RELAXED, __HIP_MEMORY_SCOPE_SYSTEM);
    if (threadIdx.x < 64) {
        int l = threadIdx.x;
        for (;;) {
            int a = __hip_atomic_load(flags + l,       __ATOMIC_RELAXED, __HIP_MEMORY_SCOPE_SYSTEM);
            int b = __hip_atomic_load(flags + l + 64,  __ATOMIC_RELAXED, __HIP_MEMORY_SCOPE_SYSTEM);
            int c = __hip_atomic_load(flags + l + 128, __ATOMIC_RELAXED, __HIP_MEMORY_SCOPE_SYSTEM);
            int d = __hip_atomic_load(flags + l + 192, __ATOMIC_RELAXED, __HIP_MEMORY_SCOPE_SYSTEM);
            if (__all(a >= phase && b >= phase && c >= phase && d >= phase)) break;
            __builtin_amdgcn_s_sleep(1);
        }
    }
    __syncthreads();   // also a compiler memory barrier: no load hoisting
}

// padded-64 unrolled gather (masked by deg) + GRU(residual)
__device__ __forceinline__ float gather_gru(int n, int s, int deg,
        const int* bucket, const int* ocnt, const int* olist,
        const float* msg_in, const float* st_in,
        const float* Wih, const float* Whh,
        const float* bih, const float* bhh) {
    const int* bk = bucket + n * BKT;
    int i0 = bk[s], i1 = bk[SS + s];
    float acc = 0.f;
#pragma unroll
    for (int k = 0; k < 32; k++) {
        int bsrc = __shfl(i0, k, 32);
        int src = (k < deg) ? bsrc : 0;          // clamp to valid row
        float v = msg_in[src * SS + s];
        acc += (k < deg) ? v : 0.f;              // mask value
    }
#pragma unroll
    for (int k = 0; k < 32; k++) {
        int kk = 32 + k;
        int bsrc = __shfl(i1, k, 32);
        int src = (kk < deg) ? bsrc : 0;
        float v = msg_in[src * SS + s];
        acc += (kk < deg) ? v : 0.f;
    }
    if (deg > BKT) {                              // correctness guard, expected never
        int oc = *ocnt; if (oc > OCAP) oc = OCAP;
        for (int i = 0; i < oc; i++)
            if (olist[2 * i + 1] == n) acc += msg_in[olist[2 * i] * SS + s];
    }
    float h0 = st_in[n * SS + s];
    float xr = bih[s], xz = bih[SS + s], xn = bih[2 * SS + s];
    float hr = bhh[s], hz = bhh[SS + s], hn = bhh[2 * SS + s];
#pragma unroll
    for (int k = 0; k < SS; k++) {
        float av = __shfl(acc, k, 32);
        float hv = __shfl(h0, k, 32);
        const float* wi = Wih + k * 3 * SS;
        const float* wh = Whh + k * 3 * SS;
        xr += av * wi[s];
        xz += av * wi[SS + s];
        xn += av * wi[2 * SS + s];
        hr += hv * wh[s];
        hz += hv * wh[SS + s];
        hn += hv * wh[2 * SS + s];
    }
    float rg = fsig(xr + hr);
    float zg = fsig(xz + hz);
    float ng = ftanh(xn + rg * hn);
    return h0 + (1.f - zg) * ng + zg * h0;
}

// Fused GNN: 256 blocks x 256 threads (1 block/CU), 3 fence-free grid barriers.
// 65536 threads = 2048 nodes x 32 lanes = 65536 edges.
__global__ void __launch_bounds__(256) gnn(Params p) {
    int tid = threadIdx.x;
    int gid = blockIdx.x * 256 + tid;
    int n = gid >> 5, s = gid & 31;

    // ---- Phase 0: encoder + msg0 (write-through); bucket fill ----
    {
        int e = gid;
        int src = p.ei[e], dst = p.ei[EE + e];
        int slot = atomicAdd(&p.cnt[dst], 1);
        if (slot < BKT) stwt_i(&p.bucket[dst * BKT + slot], src);
        else {
            int oi = atomicAdd(p.ocnt, 1);
            if (oi < OCAP) { stwt_i(&p.olist[2 * oi], src); stwt_i(&p.olist[2 * oi + 1], dst); }
        }
        const float* xr = p.x + n * FF;
        float acc = p.b_in[s];
#pragma unroll
        for (int k = 0; k < FF; k++) acc += xr[k] * p.W_in[k * SS + s];
        float st = fmaxf(acc, 0.f);
        p.st0[n * SS + s] = st;                   // own-thread reuse: plain store
        float m = p.b_msg[s];
#pragma unroll
        for (int k = 0; k < SS; k++) m += __shfl(st, k, 32) * p.W_msg[k * SS + s];
        stwt(&p.msg0[n * SS + s], fmaxf(m, 0.f)); // cross-block: write-through
    }
    gbar(p.flags, 1);

    int deg = p.cnt[n];

    // ---- Phase 1: round 0 (msg0,st0 -> st1,msg1) ----
    {
        float st = gather_gru(n, s, deg, p.bucket, p.ocnt, p.olist, p.msg0, p.st0,
                              p.W_ih, p.W_hh, p.b_ih, p.b_hh);
        p.st1[n * SS + s] = st;
        const float* Wm = p.W_msg + 1 * SS * SS;
        const float* bm = p.b_msg + 1 * SS;
        float mv = bm[s];
#pragma unroll
        for (int k = 0; k < SS; k++) mv += __shfl(st, k, 32) * Wm[k * SS + s];
        stwt(&p.msg1[n * SS + s], fmaxf(mv, 0.f));
    }
    gbar(p.flags, 2);

    // ---- Phase 2: round 1 (msg1,st1 -> st2,msg2) ----
    {
        float st = gather_gru(n, s, deg, p.bucket, p.ocnt, p.olist, p.msg1, p.st1,
                              p.W_ih + SS * 3 * SS, p.W_hh + SS * 3 * SS,
                              p.b_ih + 3 * SS, p.b_hh + 3 * SS);
        p.st2[n * SS + s] = st;
        const float* Wm = p.W_msg + 2 * SS * SS;
        const float* bm = p.b_msg + 2 * SS;
        float mv = bm[s];
#pragma unroll
        for (int k = 0; k < SS; k++) mv += __shfl(st, k, 32) * Wm[k * SS + s];
        stwt(&p.msg2[n * SS + s], fmaxf(mv, 0.f));
    }
    gbar(p.flags, 3);

    // ---- Phase 3: round 2 + heads + decoder operands ----
    {
        float st = gather_gru(n, s, deg, p.bucket, p.ocnt, p.olist, p.msg2, p.st2,
                              p.W_ih + 2 * SS * 3 * SS, p.W_hh + 2 * SS * 3 * SS,
                              p.b_ih + 2 * 3 * SS, p.b_hh + 2 * 3 * SS);
        int l = s & 15;
        const float* W = (s < 16) ? p.W_mu : p.W_ls;
        float v = (s < 16) ? p.b_mu[l] : p.b_ls[l];
#pragma unroll
        for (int k = 0; k < SS; k++) v += __shfl(st, k, 32) * W[k * LL + l];
        if (s < 16) p.out_mu[n * LL + l] = v; else p.out_ls[n * LL + l] = v;
        // A' = mu@W_d1[:L]+b_d1 (lanes 0-15), B = mu@W_d1[L:] (lanes 16-31);
        // mu row lives in lanes 0..15 so shfl k<16 is valid for all lanes.
        // A/B consumed by the NEXT dispatch -> kernel boundary handles coherence.
        const float* Wd = p.W_d1 + ((s < 16) ? 0 : LL * LL);
        float ab = (s < 16) ? p.b_d1[l] : 0.f;
#pragma unroll
        for (int k = 0; k < LL; k++) ab += __shfl(v, k, 32) * Wd[k * LL + l];
        if (s < 16) p.Abuf[n * LL + l] = ab; else p.Bbuf[n * LL + l] = ab;
    }
}

// Triangular-tiled decoder: 64x64 (bi,bj) tile with bi<=bj, computes symmetric
// prob once per unordered pair, writes tile + transpose (via LDS, coalesced).
__global__ __launch_bounds__(256) void dec_kernel(const float* __restrict__ Abuf,
                                                  const float* __restrict__ Bbuf,
                                                  const float* __restrict__ W_d2,
                                                  const float* __restrict__ b_d2,
                                                  float* __restrict__ out) {
    __shared__ float ldsAj[LL * 64];
    __shared__ float ldsBj[LL * 64];
    __shared__ float ldsT[64 * 65];
    int t = blockIdx.x;
    int bi = (int)((65.f - sqrtf(4225.f - 8.f * (float)t)) * 0.5f);
    if (bi < 0) bi = 0;
    if (bi > 31) bi = 31;
    while (bi > 0 && (65 * bi - bi * bi) / 2 > t) bi--;
    while (bi < 31 && (65 * (bi + 1) - (bi + 1) * (bi + 1)) / 2 <= t) bi++;
    int bj = bi + (t - (65 * bi - bi * bi) / 2);
    int i0 = bi * 64, j0 = bj * 64;
    int tid = threadIdx.x;

    {   // stage j-side rows transposed into LDS (coalesced global float4 loads)
        int jr = tid >> 2, q = tid & 3;
        float4 va = ((const float4*)(Abuf + (size_t)(j0 + jr) * LL))[q];
        float4 vb = ((const float4*)(Bbuf + (size_t)(j0 + jr) * LL))[q];
        int l4 = q * 4;
        ldsAj[(l4 + 0) * 64 + jr] = va.x; ldsAj[(l4 + 1) * 64 + jr] = va.y;
        ldsAj[(l4 + 2) * 64 + jr] = va.z; ldsAj[(l4 + 3) * 64 + jr] = va.w;
        ldsBj[(l4 + 0) * 64 + jr] = vb.x; ldsBj[(l4 + 1) * 64 + jr] = vb.y;
        ldsBj[(l4 + 2) * 64 + jr] = vb.z; ldsBj[(l4 + 3) * 64 + jr] = vb.w;
    }
    __syncthreads();

    int jo = tid & 63;   // j lane
    int ig = tid >> 6;   // i sub-group 0..3
    float aj[LL], bjr[LL], w[LL];
#pragma unroll
    for (int l = 0; l < LL; l++) {
        aj[l] = ldsAj[l * 64 + jo];
        bjr[l] = ldsBj[l * 64 + jo];
        w[l] = W_d2[l];
    }
    float bd2 = b_d2[0];
    int j = j0 + jo;

#pragma unroll 2
    for (int ii = 0; ii < 16; ii++) {
        int i = i0 + ig * 16 + ii;
        const float4* Ai4 = (const float4*)(Abuf + (size_t)i * LL);
        const float4* Bi4 = (const float4*)(Bbuf + (size_t)i * LL);
        float4 a0 = Ai4[0], a1 = Ai4[1], a2 = Ai4[2], a3 = Ai4[3];
        float4 b0 = Bi4[0], b1 = Bi4[1], b2 = Bi4[2], b3 = Bi4[3];
        float ai[LL] = {a0.x, a0.y, a0.z, a0.w, a1.x, a1.y, a1.z, a1.w,
                        a2.x, a2.y, a2.z, a2.w, a3.x, a3.y, a3.z, a3.w};
        float bi_[LL] = {b0.x, b0.y, b0.z, b0.w, b1.x, b1.y, b1.z, b1.w,
                         b2.x, b2.y, b2.z, b2.w, b3.x, b3.y, b3.z, b3.w};
        float accij = 0.f, accji = 0.f;
#pragma unroll
        for (int l = 0; l < LL; l++) {
            accij += w[l] * fmaxf(ai[l] + bjr[l], 0.f);
            accji += w[l] * fmaxf(aj[l] + bi_[l], 0.f);
        }
        float logit = 0.5f * (accij + accji) + bd2;
        float p = 1.f / (1.f + __expf(-logit));
        out[(size_t)i * NN + j] = p;
        ldsT[jo * 65 + ig * 16 + ii] = p;
    }

    if (bi != bj) {  // transposed tile write via LDS (coalesced)
        __syncthreads();
        int jj = tid >> 2, qi = tid & 3;
        float v[16];
#pragma unroll
        for (int m = 0; m < 16; m++) v[m] = ldsT[jj * 65 + qi * 16 + m];
        float4* dst = (float4*)(out + (size_t)(j0 + jj) * NN + i0 + qi * 16);
#pragma unroll
        for (int q4 = 0; q4 < 4; q4++)
            dst[q4] = make_float4(v[4 * q4], v[4 * q4 + 1], v[4 * q4 + 2], v[4 * q4 + 3]);
    }
}

extern "C" void kernel_launch(void* const* d_in, const int* in_sizes, int n_in,
                              void* d_out, int out_size, void* d_ws, size_t ws_size,
                              hipStream_t stream) {
    Params p;
    p.x     = (const float*)d_in[0];
    p.ei    = (const int*)d_in[1];
    p.W_in  = (const float*)d_in[2];
    p.b_in  = (const float*)d_in[3];
    p.W_msg = (const float*)d_in[4];
    p.b_msg = (const float*)d_in[5];
    p.W_ih  = (const float*)d_in[6];
    p.W_hh  = (const float*)d_in[7];
    p.b_ih  = (const float*)d_in[8];
    p.b_hh  = (const float*)d_in[9];
    p.W_mu  = (const float*)d_in[10];
    p.b_mu  = (const float*)d_in[11];
    p.W_ls  = (const float*)d_in[12];
    p.b_ls  = (const float*)d_in[13];
    p.W_d1  = (const float*)d_in[14];
    p.b_d1  = (const float*)d_in[15];
    const float* W_d2 = (const float*)d_in[16];
    const float* b_d2 = (const float*)d_in[17];

    float* ws = (float*)d_ws;
    p.st0  = ws;                        // N*S
    p.st1  = p.st0 + NN * SS;           // N*S
    p.st2  = p.st1 + NN * SS;           // N*S
    p.msg0 = p.st2 + NN * SS;           // N*S
    p.msg1 = p.msg0 + NN * SS;          // N*S
    p.msg2 = p.msg1 + NN * SS;          // N*S
    p.Abuf = p.msg2 + NN * SS;          // N*L
    p.Bbuf = p.Abuf + NN * LL;          // N*L
    p.cnt  = (int*)(p.Bbuf + NN * LL);  // N      (memset region start)
    p.ocnt = p.cnt + NN;                // 1
    p.flags = p.ocnt + 1;               // NBLK   (memset region end)
    p.olist = p.flags + NBLK;           // 2*OCAP
    p.bucket = p.olist + 2 * OCAP;      // N*BKT

    float* out_adj = (float*)d_out;
    p.out_mu  = out_adj + (size_t)NN * NN;
    p.out_ls  = p.out_mu + NN * LL;

    // zero cnt + ocnt + barrier flags (one small memset, graph-capturable)
    hipMemsetAsync(p.cnt, 0, (NN + 1 + NBLK) * sizeof(int), stream);

    gnn<<<NBLK, 256, 0, stream>>>(p);

    dec_kernel<<<528, 256, 0, stream>>>(p.Abuf, p.Bbuf, W_d2, b_d2, out_adj);
}

// Round 9
// 60.167 us; speedup vs baseline: 3.4378x; 1.1396x over previous
//
#include <hip/hip_runtime.h>
#include <math.h>

#define NN 2048
#define EE 65536
#define FF 7
#define SS 32
#define LL 16
#define BKT 64     // bucket slots per node, compile-time unrolled gather
#define OCAP 4096  // overflow capacity for deg > 64 (expected 0, correctness guard)
#define NBLK 256   // grid size (1 block per CU, co-resident)

struct Params {
    const float *x; const int *ei;
    const float *W_in, *b_in, *W_msg, *b_msg, *W_ih, *W_hh, *b_ih, *b_hh;
    const float *W_mu, *b_mu, *W_ls, *b_ls, *W_d1, *b_d1;
    float *msg0, *msg1, *msg2, *Abuf, *Bbuf;
    int *cnt, *ocnt, *olist, *bucket, *flags, *go;
    float *out_mu, *out_ls;
};

__device__ __forceinline__ float fsig(float x) { return 1.f / (1.f + __expf(-x)); }
__device__ __forceinline__ float ftanh(float x) { return 1.f - 2.f / (__expf(2.f * x) + 1.f); }

// write-through store (to coherent point); relaxed, no fence
__device__ __forceinline__ void stwt(float* p, float v) {
    __hip_atomic_store(p, v, __ATOMIC_RELAXED, __HIP_MEMORY_SCOPE_SYSTEM);
}
__device__ __forceinline__ void stwt_i(int* p, int v) {
    __hip_atomic_store(p, v, __ATOMIC_RELAXED, __HIP_MEMORY_SCOPE_SYSTEM);
}
__device__ __forceinline__ int ldsys(const int* p) {
    return __hip_atomic_load(p, __ATOMIC_RELAXED, __HIP_MEMORY_SCOPE_SYSTEM);
}

// Two-hop fence-free grid barrier:
//   arrive: each block's leader stores flags[bid]=phase   (no contention)
//   block 0 wave 0 sweeps all 256 flags (single-CU poll traffic), sets go
//   other blocks poll the single go word with sleep backoff
// Data correctness: cross-block data written via stwt (coherent point) and
// drained by the __syncthreads() vmcnt(0) before the flag store.
// flags/go zeroed by host memset each call; phase = 1,2,3 monotone per call.
__device__ __forceinline__ void gbar(int* flags, int* go, int phase) {
    __syncthreads();
    if (blockIdx.x == 0) {
        if (threadIdx.x < 64) {
            if (threadIdx.x == 0)
                stwt_i(flags + 0, phase);
            int l = threadIdx.x;
            for (;;) {
                int a = ldsys(flags + l);
                int b = ldsys(flags + l + 64);
                int c = ldsys(flags + l + 128);
                int d = ldsys(flags + l + 192);
                if (__all(a >= phase && b >= phase && c >= phase && d >= phase)) break;
                __builtin_amdgcn_s_sleep(2);
            }
            if (threadIdx.x == 0)
                stwt_i(go, phase);
        }
    } else if (threadIdx.x == 0) {
        stwt_i(flags + blockIdx.x, phase);
        while (ldsys(go) < phase) __builtin_amdgcn_s_sleep(8);
    }
    __syncthreads();
}

// padded-64 unrolled gather (masked by deg) + GRU(residual); state in register.
__device__ __forceinline__ float gather_gru(int s, int deg, int i0, int i1,
        const int* ocnt, const int* olist, int n,
        const float* msg_in, float h0,
        const float* Wih, const float* Whh,
        const float* bih, const float* bhh) {
    float acc = 0.f;
#pragma unroll
    for (int k = 0; k < 32; k++) {
        int bsrc = __shfl(i0, k, 32);
        int src = (k < deg) ? bsrc : 0;          // clamp to valid row
        float v = msg_in[src * SS + s];
        acc += (k < deg) ? v : 0.f;              // mask value
    }
#pragma unroll
    for (int k = 0; k < 32; k++) {
        int kk = 32 + k;
        int bsrc = __shfl(i1, k, 32);
        int src = (kk < deg) ? bsrc : 0;
        float v = msg_in[src * SS + s];
        acc += (kk < deg) ? v : 0.f;
    }
    if (deg > BKT) {                              // correctness guard, expected never
        int oc = *ocnt; if (oc > OCAP) oc = OCAP;
        for (int i = 0; i < oc; i++)
            if (olist[2 * i + 1] == n) acc += msg_in[olist[2 * i] * SS + s];
    }
    float xr = bih[s], xz = bih[SS + s], xn = bih[2 * SS + s];
    float hr = bhh[s], hz = bhh[SS + s], hn = bhh[2 * SS + s];
#pragma unroll
    for (int k = 0; k < SS; k++) {
        float av = __shfl(acc, k, 32);
        float hv = __shfl(h0, k, 32);
        const float* wi = Wih + k * 3 * SS;
        const float* wh = Whh + k * 3 * SS;
        xr += av * wi[s];
        xz += av * wi[SS + s];
        xn += av * wi[2 * SS + s];
        hr += hv * wh[s];
        hz += hv * wh[SS + s];
        hn += hv * wh[2 * SS + s];
    }
    float rg = fsig(xr + hr);
    float zg = fsig(xz + hz);
    float ng = ftanh(xn + rg * hn);
    return h0 + (1.f - zg) * ng + zg * h0;
}

// Fused GNN: 256 blocks x 256 threads (1 block/CU), 3 two-hop grid barriers.
// 65536 threads = 2048 nodes x 32 lanes = 65536 edges. Hidden state in VGPR.
__global__ void __launch_bounds__(256) gnn(Params p) {
    int tid = threadIdx.x;
    int gid = blockIdx.x * 256 + tid;
    int n = gid >> 5, s = gid & 31;

    float stc;   // GRU hidden state for (n,s) — only ever used by this thread

    // ---- Phase 0: encoder + msg0 (write-through); bucket fill ----
    {
        int e = gid;
        int src = p.ei[e], dst = p.ei[EE + e];
        int slot = atomicAdd(&p.cnt[dst], 1);
        if (slot < BKT) stwt_i(&p.bucket[dst * BKT + slot], src);
        else {
            int oi = atomicAdd(p.ocnt, 1);
            if (oi < OCAP) { stwt_i(&p.olist[2 * oi], src); stwt_i(&p.olist[2 * oi + 1], dst); }
        }
        const float* xr = p.x + n * FF;
        float acc = p.b_in[s];
#pragma unroll
        for (int k = 0; k < FF; k++) acc += xr[k] * p.W_in[k * SS + s];
        stc = fmaxf(acc, 0.f);
        float m = p.b_msg[s];
#pragma unroll
        for (int k = 0; k < SS; k++) m += __shfl(stc, k, 32) * p.W_msg[k * SS + s];
        stwt(&p.msg0[n * SS + s], fmaxf(m, 0.f)); // cross-block: write-through
    }
    gbar(p.flags, p.go, 1);

    // bucket row + degree: loaded once, reused in all 3 rounds
    int deg = p.cnt[n];
    int i0 = p.bucket[n * BKT + s];
    int i1 = p.bucket[n * BKT + SS + s];

    // ---- Phase 1: round 0 (msg0 -> msg1) ----
    {
        stc = gather_gru(s, deg, i0, i1, p.ocnt, p.olist, n, p.msg0, stc,
                         p.W_ih, p.W_hh, p.b_ih, p.b_hh);
        const float* Wm = p.W_msg + 1 * SS * SS;
        const float* bm = p.b_msg + 1 * SS;
        float mv = bm[s];
#pragma unroll
        for (int k = 0; k < SS; k++) mv += __shfl(stc, k, 32) * Wm[k * SS + s];
        stwt(&p.msg1[n * SS + s], fmaxf(mv, 0.f));
    }
    gbar(p.flags, p.go, 2);

    // ---- Phase 2: round 1 (msg1 -> msg2) ----
    {
        stc = gather_gru(s, deg, i0, i1, p.ocnt, p.olist, n, p.msg1, stc,
                         p.W_ih + SS * 3 * SS, p.W_hh + SS * 3 * SS,
                         p.b_ih + 3 * SS, p.b_hh + 3 * SS);
        const float* Wm = p.W_msg + 2 * SS * SS;
        const float* bm = p.b_msg + 2 * SS;
        float mv = bm[s];
#pragma unroll
        for (int k = 0; k < SS; k++) mv += __shfl(stc, k, 32) * Wm[k * SS + s];
        stwt(&p.msg2[n * SS + s], fmaxf(mv, 0.f));
    }
    gbar(p.flags, p.go, 3);

    // ---- Phase 3: round 2 + heads + decoder operands ----
    {
        stc = gather_gru(s, deg, i0, i1, p.ocnt, p.olist, n, p.msg2, stc,
                         p.W_ih + 2 * SS * 3 * SS, p.W_hh + 2 * SS * 3 * SS,
                         p.b_ih + 2 * 3 * SS, p.b_hh + 2 * 3 * SS);
        int l = s & 15;
        const float* W = (s < 16) ? p.W_mu : p.W_ls;
        float v = (s < 16) ? p.b_mu[l] : p.b_ls[l];
#pragma unroll
        for (int k = 0; k < SS; k++) v += __shfl(stc, k, 32) * W[k * LL + l];
        if (s < 16) p.out_mu[n * LL + l] = v; else p.out_ls[n * LL + l] = v;
        // A' = mu@W_d1[:L]+b_d1 (lanes 0-15), B = mu@W_d1[L:] (lanes 16-31);
        // mu row lives in lanes 0..15 so shfl k<16 is valid for all lanes.
        // A/B consumed by the NEXT dispatch -> kernel boundary handles coherence.
        const float* Wd = p.W_d1 + ((s < 16) ? 0 : LL * LL);
        float ab = (s < 16) ? p.b_d1[l] : 0.f;
#pragma unroll
        for (int k = 0; k < LL; k++) ab += __shfl(v, k, 32) * Wd[k * LL + l];
        if (s < 16) p.Abuf[n * LL + l] = ab; else p.Bbuf[n * LL + l] = ab;
    }
}

// Triangular-tiled decoder: 64x64 (bi,bj) tile with bi<=bj, computes symmetric
// prob once per unordered pair, writes tile + transpose (via LDS, coalesced).
__global__ __launch_bounds__(256) void dec_kernel(const float* __restrict__ Abuf,
                                                  const float* __restrict__ Bbuf,
                                                  const float* __restrict__ W_d2,
                                                  const float* __restrict__ b_d2,
                                                  float* __restrict__ out) {
    __shared__ float ldsAj[LL * 64];
    __shared__ float ldsBj[LL * 64];
    __shared__ float ldsT[64 * 65];
    int t = blockIdx.x;
    int bi = (int)((65.f - sqrtf(4225.f - 8.f * (float)t)) * 0.5f);
    if (bi < 0) bi = 0;
    if (bi > 31) bi = 31;
    while (bi > 0 && (65 * bi - bi * bi) / 2 > t) bi--;
    while (bi < 31 && (65 * (bi + 1) - (bi + 1) * (bi + 1)) / 2 <= t) bi++;
    int bj = bi + (t - (65 * bi - bi * bi) / 2);
    int i0 = bi * 64, j0 = bj * 64;
    int tid = threadIdx.x;

    {   // stage j-side rows transposed into LDS (coalesced global float4 loads)
        int jr = tid >> 2, q = tid & 3;
        float4 va = ((const float4*)(Abuf + (size_t)(j0 + jr) * LL))[q];
        float4 vb = ((const float4*)(Bbuf + (size_t)(j0 + jr) * LL))[q];
        int l4 = q * 4;
        ldsAj[(l4 + 0) * 64 + jr] = va.x; ldsAj[(l4 + 1) * 64 + jr] = va.y;
        ldsAj[(l4 + 2) * 64 + jr] = va.z; ldsAj[(l4 + 3) * 64 + jr] = va.w;
        ldsBj[(l4 + 0) * 64 + jr] = vb.x; ldsBj[(l4 + 1) * 64 + jr] = vb.y;
        ldsBj[(l4 + 2) * 64 + jr] = vb.z; ldsBj[(l4 + 3) * 64 + jr] = vb.w;
    }
    __syncthreads();

    int jo = tid & 63;   // j lane
    int ig = tid >> 6;   // i sub-group 0..3
    float aj[LL], bjr[LL], w[LL];
#pragma unroll
    for (int l = 0; l < LL; l++) {
        aj[l] = ldsAj[l * 64 + jo];
        bjr[l] = ldsBj[l * 64 + jo];
        w[l] = W_d2[l];
    }
    float bd2 = b_d2[0];
    int j = j0 + jo;

#pragma unroll 2
    for (int ii = 0; ii < 16; ii++) {
        int i = i0 + ig * 16 + ii;
        const float4* Ai4 = (const float4*)(Abuf + (size_t)i * LL);
        const float4* Bi4 = (const float4*)(Bbuf + (size_t)i * LL);
        float4 a0 = Ai4[0], a1 = Ai4[1], a2 = Ai4[2], a3 = Ai4[3];
        float4 b0 = Bi4[0], b1 = Bi4[1], b2 = Bi4[2], b3 = Bi4[3];
        float ai[LL] = {a0.x, a0.y, a0.z, a0.w, a1.x, a1.y, a1.z, a1.w,
                        a2.x, a2.y, a2.z, a2.w, a3.x, a3.y, a3.z, a3.w};
        float bi_[LL] = {b0.x, b0.y, b0.z, b0.w, b1.x, b1.y, b1.z, b1.w,
                         b2.x, b2.y, b2.z, b2.w, b3.x, b3.y, b3.z, b3.w};
        float accij = 0.f, accji = 0.f;
#pragma unroll
        for (int l = 0; l < LL; l++) {
            accij += w[l] * fmaxf(ai[l] + bjr[l], 0.f);
            accji += w[l] * fmaxf(aj[l] + bi_[l], 0.f);
        }
        float logit = 0.5f * (accij + accji) + bd2;
        float p = 1.f / (1.f + __expf(-logit));
        out[(size_t)i * NN + j] = p;
        ldsT[jo * 65 + ig * 16 + ii] = p;
    }

    if (bi != bj) {  // transposed tile write via LDS (coalesced)
        __syncthreads();
        int jj = tid >> 2, qi = tid & 3;
        float v[16];
#pragma unroll
        for (int m = 0; m < 16; m++) v[m] = ldsT[jj * 65 + qi * 16 + m];
        float4* dst = (float4*)(out + (size_t)(j0 + jj) * NN + i0 + qi * 16);
#pragma unroll
        for (int q4 = 0; q4 < 4; q4++)
            dst[q4] = make_float4(v[4 * q4], v[4 * q4 + 1], v[4 * q4 + 2], v[4 * q4 + 3]);
    }
}

extern "C" void kernel_launch(void* const* d_in, const int* in_sizes, int n_in,
                              void* d_out, int out_size, void* d_ws, size_t ws_size,
                              hipStream_t stream) {
    Params p;
    p.x     = (const float*)d_in[0];
    p.ei    = (const int*)d_in[1];
    p.W_in  = (const float*)d_in[2];
    p.b_in  = (const float*)d_in[3];
    p.W_msg = (const float*)d_in[4];
    p.b_msg = (const float*)d_in[5];
    p.W_ih  = (const float*)d_in[6];
    p.W_hh  = (const float*)d_in[7];
    p.b_ih  = (const float*)d_in[8];
    p.b_hh  = (const float*)d_in[9];
    p.W_mu  = (const float*)d_in[10];
    p.b_mu  = (const float*)d_in[11];
    p.W_ls  = (const float*)d_in[12];
    p.b_ls  = (const float*)d_in[13];
    p.W_d1  = (const float*)d_in[14];
    p.b_d1  = (const float*)d_in[15];
    const float* W_d2 = (const float*)d_in[16];
    const float* b_d2 = (const float*)d_in[17];

    float* ws = (float*)d_ws;
    p.msg0 = ws;                        // N*S
    p.msg1 = p.msg0 + NN * SS;          // N*S
    p.msg2 = p.msg1 + NN * SS;          // N*S
    p.Abuf = p.msg2 + NN * SS;          // N*L
    p.Bbuf = p.Abuf + NN * LL;          // N*L
    p.cnt  = (int*)(p.Bbuf + NN * LL);  // N      (memset region start)
    p.ocnt = p.cnt + NN;                // 1
    p.flags = p.ocnt + 1;               // NBLK
    p.go   = p.flags + NBLK;            // 4      (memset region end)
    p.olist = p.go + 4;                 // 2*OCAP
    p.bucket = p.olist + 2 * OCAP;      // N*BKT

    float* out_adj = (float*)d_out;
    p.out_mu  = out_adj + (size_t)NN * NN;
    p.out_ls  = p.out_mu + NN * LL;

    // zero cnt + ocnt + flags + go (one small memset, graph-capturable)
    hipMemsetAsync(p.cnt, 0, (NN + 1 + NBLK + 4) * sizeof(int), stream);

    gnn<<<NBLK, 256, 0, stream>>>(p);

    dec_kernel<<<528, 256, 0, stream>>>(p.Abuf, p.Bbuf, W_d2, b_d2, out_adj);
}